// Round 4
// baseline (94.668 us; speedup 1.0000x reference)
//
#include <hip/hip_runtime.h>

// Tropical (max-plus) linear layer:
//   out[b, j] = max_k (x[b,k] + w[j,k]) + bias[j]   if any product > -1e38
//             = -1e38                                otherwise
// x: [4096, 256] f32, w: [256, 256] f32, bias: [256] f32, out: [4096, 256] f32
//
// R4 structure: register-resident w, scalar-broadcast x, LDS-free K-loop.
//  - lane = output column (64 cols/block); split-K over 4 waves,
//    wave q holds w[col][64q .. 64q+63] in 64 VGPRs (loaded once per block)
//  - x chunk addresses are wave-uniform -> s_load_dwordx4; the scalar value
//    feeds v_add_f32 as the one allowed SGPR operand. No ds_read, no barrier,
//    no lgkm DS/SMEM mixing in the hot loop.
//  - split-K partials combined via one 16 KB LDS pass at the end.

#define TZERO -1e38f

constexpr int K     = 256;
constexpr int N     = 256;
constexpr int Bdim  = 4096;
constexpr int BN    = 64;           // cols per block (= lanes)
constexpr int RPB   = 16;           // rows per block
constexpr int WAVES = 4;            // split-K factor
constexpr int KQ    = K / WAVES;    // 64 k per wave
constexpr int NT    = 64 * WAVES;   // 256 threads

__global__ __launch_bounds__(NT, 4)
void tropical_kernel(const float* __restrict__ x, const float* __restrict__ w,
                     const float* __restrict__ bias, float* __restrict__ out)
{
    __shared__ float red[WAVES][RPB][BN];   // 16 KB, epilogue only

    const int t    = threadIdx.x;
    const int lane = t & 63;
    const int wave = __builtin_amdgcn_readfirstlane(t >> 6);
    const int row0 = blockIdx.x * RPB;
    const int col0 = blockIdx.y * BN;

    // ---- w chunk -> VGPRs: wr[i] = w[col0+lane][wave*KQ + i]
    //      (per-lane 1 KB stride gather; one-time, L2-resident)
    float wr[KQ];
    {
        const float* wp = w + (size_t)(col0 + lane) * K + wave * KQ;
#pragma unroll
        for (int i4 = 0; i4 < KQ / 4; ++i4) {
            const float4 v = *reinterpret_cast<const float4*>(wp + i4 * 4);
            wr[i4 * 4 + 0] = v.x;
            wr[i4 * 4 + 1] = v.y;
            wr[i4 * 4 + 2] = v.z;
            wr[i4 * 4 + 3] = v.w;
        }
    }

    // ---- stream rows; all x addresses wave-uniform -> scalar load path
    const float* xq = x + (size_t)row0 * K + wave * KQ;

    float acc[RPB];
#pragma unroll 1
    for (int r = 0; r < RPB; ++r) {
        const float* xr = xq + (size_t)r * K;
        float m = -__builtin_inff();
#pragma unroll
        for (int i4 = 0; i4 < KQ / 4; ++i4) {
            const float4 xv = *reinterpret_cast<const float4*>(xr + i4 * 4);
            const float t0 = xv.x + wr[i4 * 4 + 0];
            const float t1 = xv.y + wr[i4 * 4 + 1];
            const float t2 = xv.z + wr[i4 * 4 + 2];
            const float t3 = xv.w + wr[i4 * 4 + 3];
            m = fmaxf(fmaxf(m, t0), t1);   // v_max3_f32
            m = fmaxf(fmaxf(m, t2), t3);   // v_max3_f32
        }
        acc[r] = m;
    }

    // ---- split-K reduction through LDS (conflict-free b32, lane-contiguous)
#pragma unroll
    for (int r = 0; r < RPB; ++r) red[wave][r][lane] = acc[r];
    __syncthreads();

    const int rbase = wave * (RPB / WAVES);
    const float bj  = bias[col0 + lane];
#pragma unroll
    for (int i = 0; i < RPB / WAVES; ++i) {
        const int r = rbase + i;
        const float m = fmaxf(fmaxf(red[0][r][lane], red[1][r][lane]),
                              fmaxf(red[2][r][lane], red[3][r][lane]));
        out[(size_t)(row0 + r) * N + col0 + lane] =
            (m > TZERO) ? m + bj : TZERO;
    }
}

extern "C" void kernel_launch(void* const* d_in, const int* in_sizes, int n_in,
                              void* d_out, int out_size, void* d_ws, size_t ws_size,
                              hipStream_t stream) {
    const float* x  = (const float*)d_in[0];
    const float* w  = (const float*)d_in[1];
    const float* b  = (const float*)d_in[2];
    float* out      = (float*)d_out;

    dim3 grid(Bdim / RPB, N / BN);   // (256, 4) = 1024 blocks, 4 waves each
    tropical_kernel<<<grid, NT, 0, stream>>>(x, w, b, out);
}

// Round 5
// 74.670 us; speedup vs baseline: 1.2678x; 1.2678x over previous
//
#include <hip/hip_runtime.h>

// Tropical (max-plus) linear layer:
//   out[b, j] = max_k (x[b,k] + w[j,k]) + bias[j]   if any product > -1e38
//             = -1e38                                otherwise
// x: [4096, 256] f32, w: [256, 256] f32, bias: [256] f32, out: [4096, 256] f32
//
// R5 structure: x in VGPRs (vector path), w wave-uniform (scalar path),
// LDS-free barrier-free hot loop, split-K×8 with one LDS reduce at the end.
//  - lane = row (64 rows/block), wave = k-chunk (KQ=32 -> xr[32] VGPRs, no
//    spill), j-loop over 32 output cols
//  - per j: 8 wave-uniform float4 loads of w (s_load path, w is 32 KB/block
//    and reused -> cache-resident) + 32 v_add_f32 + 16 v_max3_f32
//  - grid 512 blocks = exactly 2 blocks/CU resident, 16 waves/CU (4/SIMD)

#define TZERO -1e38f

constexpr int K    = 256;
constexpr int N    = 256;
constexpr int Bdim = 4096;
constexpr int BN   = 32;            // cols per block
constexpr int SKW  = 8;             // split-K waves per block
constexpr int KQ   = K / SKW;       // 32 k per wave
constexpr int NT   = 64 * SKW;      // 512 threads
constexpr int RPB  = 64;            // rows per block (= lanes)

__global__ __launch_bounds__(NT, 4)
void tropical_kernel(const float* __restrict__ x, const float* __restrict__ w,
                     const float* __restrict__ bias, float* __restrict__ out)
{
    __shared__ float red[SKW][BN][65];   // padded: 66.5 KB, epilogue reduce

    const int t    = threadIdx.x;
    const int lane = t & 63;
    const int wave = __builtin_amdgcn_readfirstlane(t >> 6);
    const int row0 = blockIdx.x * RPB;
    const int col0 = blockIdx.y * BN;

    // ---- x chunk -> VGPRs: xr[i] = x[row0+lane][wave*KQ + i]
    //      (each wave consumes full 64B lines across its 8 loads -> no overfetch)
    float xr[KQ];
    {
        const float* xp = x + (size_t)(row0 + lane) * K + wave * KQ;
#pragma unroll
        for (int i4 = 0; i4 < KQ / 4; ++i4) {
            const float4 v = *reinterpret_cast<const float4*>(xp + i4 * 4);
            xr[i4 * 4 + 0] = v.x;
            xr[i4 * 4 + 1] = v.y;
            xr[i4 * 4 + 2] = v.z;
            xr[i4 * 4 + 3] = v.w;
        }
    }

    // ---- hot loop: w via wave-uniform loads (scalar path), no LDS, no barrier
    const float* wp0 = w + (size_t)col0 * K + wave * KQ;

#pragma unroll 2
    for (int j = 0; j < BN; ++j) {
        const float* wp = wp0 + (size_t)j * K;   // wave-uniform address
        float m = -__builtin_inff();
#pragma unroll
        for (int i4 = 0; i4 < KQ / 4; ++i4) {
            const float4 wv = *reinterpret_cast<const float4*>(wp + i4 * 4);
            const float t0 = xr[i4 * 4 + 0] + wv.x;
            const float t1 = xr[i4 * 4 + 1] + wv.y;
            const float t2 = xr[i4 * 4 + 2] + wv.z;
            const float t3 = xr[i4 * 4 + 3] + wv.w;
            m = fmaxf(fmaxf(m, t0), t1);   // v_max3_f32
            m = fmaxf(fmaxf(m, t2), t3);   // v_max3_f32
        }
        // write partial: bank = (j*65 + lane) % 32 -> 2-way alias, free
        red[wave][j][lane] = m;
    }
    __syncthreads();   // the ONLY barrier

    // ---- epilogue: reduce 8 split-K partials, bias, coalesced stores
    const int jj = t & 31;          // col within tile
    const int r0 = t >> 5;          // 0..15
    const float bj = bias[col0 + jj];
#pragma unroll
    for (int i = 0; i < 4; ++i) {
        const int r = r0 + 16 * i;  // row within tile (0..63)
        // read bank = (jj*65 + r) % 32 = (jj + r) % 32 -> conflict-free
        float m = red[0][jj][r];
#pragma unroll
        for (int q = 1; q < SKW; ++q) m = fmaxf(m, red[q][jj][r]);
        out[(size_t)(row0 + r) * N + col0 + jj] = (m > TZERO) ? m + bj : TZERO;
    }
}

extern "C" void kernel_launch(void* const* d_in, const int* in_sizes, int n_in,
                              void* d_out, int out_size, void* d_ws, size_t ws_size,
                              hipStream_t stream) {
    const float* x  = (const float*)d_in[0];
    const float* w  = (const float*)d_in[1];
    const float* b  = (const float*)d_in[2];
    float* out      = (float*)d_out;

    dim3 grid(Bdim / RPB, N / BN);   // (64, 8) = 512 blocks, 8 waves each
    tropical_kernel<<<grid, NT, 0, stream>>>(x, w, b, out);
}